// Round 4
// baseline (570.744 us; speedup 1.0000x reference)
//
#include <hip/hip_runtime.h>
#include <hip/hip_bf16.h>

#define NN 8192
#define FIN 512
#define FOUT 256

typedef __attribute__((ext_vector_type(8))) short short8;
typedef __attribute__((ext_vector_type(4))) float float4v;
typedef __attribute__((ext_vector_type(16))) float float16v;

__device__ __forceinline__ short f2bf(float f) {
    union { float f; unsigned u; } v; v.f = f;
    unsigned r = (v.u + 0x7FFFu + ((v.u >> 16) & 1u)) >> 16;
    return (short)r;
}

// ---------------- Kernel P: pack adj (256 MB) -> bitmask (8 MB), pure streaming ----------------
// Wave reads 64 contiguous ints, __ballot -> one uint64. 2048 blocks = 8/CU, 32 waves/CU.
__global__ __launch_bounds__(256) void pack_kernel(const int* __restrict__ adj,
                                                   unsigned long long* __restrict__ pk64) {
    const int tid = blockIdx.x * 256 + threadIdx.x;
    const int stride = 2048 * 256;
#pragma unroll 4
    for (int k = 0; k < (NN * NN) / stride; ++k) {
        int idx = tid + k * stride;
        unsigned long long m = __ballot(adj[idx] != 0);
        if ((threadIdx.x & 63) == 0) pk64[idx >> 6] = m;
    }
}

// ---------------- Kernel 0: Wt[n][k] = bf16(W[k][n]), tiled transpose ----------------
__global__ __launch_bounds__(256) void wt_kernel(const float* __restrict__ W,
                                                 short* __restrict__ Wt) {
    __shared__ short tile[32][33];
    int tx = threadIdx.x & 31, ty = threadIdx.x >> 5;
    int k0 = blockIdx.x * 32, n0 = blockIdx.y * 32;
#pragma unroll
    for (int r = 0; r < 32; r += 8)
        tile[ty + r][tx] = f2bf(W[(size_t)(k0 + ty + r) * FOUT + n0 + tx]);
    __syncthreads();
#pragma unroll
    for (int r = 0; r < 32; r += 8)
        Wt[(size_t)(n0 + ty + r) * FIN + k0 + tx] = tile[tx][ty + r];
}

// ---------------- Kernel 1: h_t[n][m] = bf16((x@W)[m][n]); fused f_src/f_dst ----------------
// wave = 16m x 32n tile; 1024 blocks x 4 waves = 4096 waves -> 16 waves/CU.
__global__ __launch_bounds__(256) void h_kernel(const float* __restrict__ x,
                                                const short* __restrict__ Wt,
                                                const float* __restrict__ a,
                                                short* __restrict__ h_t,
                                                float* __restrict__ f_src,
                                                float* __restrict__ f_dst) {
    int wave = (blockIdx.x << 2) + (threadIdx.x >> 6);
    int lane = threadIdx.x & 63;
    int m0 = (wave & 511) << 4;
    int n0 = (wave >> 9) << 5;
    int lr = lane & 15, lq = lane >> 4;

    const float* xrow = x + (size_t)(m0 + lr) * FIN + lq * 8;
    const short* wbase = Wt + (size_t)(n0 + lr) * FIN + lq * 8;

    float4v acc[2] = {};
    for (int k0 = 0; k0 < FIN; k0 += 32) {
        float4v xa = *(const float4v*)(xrow + k0);
        float4v xb = *(const float4v*)(xrow + k0 + 4);
        short8 av;
        av[0] = f2bf(xa[0]); av[1] = f2bf(xa[1]); av[2] = f2bf(xa[2]); av[3] = f2bf(xa[3]);
        av[4] = f2bf(xb[0]); av[5] = f2bf(xb[1]); av[6] = f2bf(xb[2]); av[7] = f2bf(xb[3]);
#pragma unroll
        for (int ct = 0; ct < 2; ct++) {
            short8 bv = *(const short8*)(wbase + (size_t)ct * 16 * FIN + k0);
            acc[ct] = __builtin_amdgcn_mfma_f32_16x16x32_bf16(av, bv, acc[ct], 0, 0, 0);
        }
    }
    float s_part[4] = {0.f, 0.f, 0.f, 0.f};
    float d_part[4] = {0.f, 0.f, 0.f, 0.f};
#pragma unroll
    for (int ct = 0; ct < 2; ct++) {
        int n = n0 + ct * 16 + lr;
        float al = a[n], ar = a[FOUT + n];
#pragma unroll
        for (int reg = 0; reg < 4; reg++) {
            float hv = acc[ct][reg];
            s_part[reg] = fmaf(hv, al, s_part[reg]);
            d_part[reg] = fmaf(hv, ar, d_part[reg]);
            h_t[(size_t)n * NN + (m0 + lq * 4 + reg)] = f2bf(hv);
        }
    }
#pragma unroll
    for (int off = 1; off < 16; off <<= 1) {
#pragma unroll
        for (int reg = 0; reg < 4; reg++) {
            s_part[reg] += __shfl_xor(s_part[reg], off);
            d_part[reg] += __shfl_xor(d_part[reg], off);
        }
    }
    const float LOG2E = 1.4426950408889634f;
    if (lr == 0) {
#pragma unroll
        for (int reg = 0; reg < 4; reg++) {
            atomicAdd(&f_src[m0 + lq * 4 + reg], s_part[reg] * LOG2E);
            atomicAdd(&f_dst[m0 + lq * 4 + reg], d_part[reg] * LOG2E);
        }
    }
}

// ---------------- Kernel 2: fused masked-softmax-numerator @ h ----------------
// All inputs L2/L3-resident (pk 8MB, h_t 4MB, f 64KB). No LDS, no barriers.
// Block: 512 thr = 8 waves = 4 row-groups x 2 feat-groups; tile 128 rows x 256 feats.
// Wave: 32 rows x 128 feats = 4 acc tiles of 32x32 (64 acc VGPR).
// Grid: (64 rowgroups, 4 slices) = 256 blocks -> 1 block/CU, 16 waves/CU.
__global__ __launch_bounds__(512, 4) void gat_kernel(const unsigned long long* __restrict__ pk64,
                                                     const short* __restrict__ h_t,
                                                     const float* __restrict__ f_src,
                                                     const float* __restrict__ f_dst,
                                                     float* __restrict__ Opart,
                                                     float* __restrict__ lpart,
                                                     int jlen) {
    const int t = threadIdx.x;
    const int lane = t & 63;
    const int w = t >> 6;
    const int l31 = lane & 31, lq = lane >> 5;
    const int wr = w & 3, wc = w >> 2;           // row-group 0..3, feat-group 0..1
    const int i0 = blockIdx.x * 128;
    const int slice = blockIdx.y;
    const int jbase = slice * jlen;
    const int r = i0 + wr * 32 + l31;            // this lane's adjacency row
    const int nchunk = jlen >> 6;

    const float fs = f_src[r];
    const unsigned long long* pkRow = pk64 + (size_t)r * (NN / 64) + (jbase >> 6);
    const short* hb = h_t + (size_t)(wc * 128 + l31) * NN + jbase + lq * 8;
    const float* fdL = f_dst + jbase + lq * 8;

    float16v acc[4] = {};
    float lp = 0.f;

    for (int c = 0; c < nchunk; ++c) {
        unsigned long long bm = pkRow[c];
        unsigned bmlo = (unsigned)bm, bmhi = (unsigned)(bm >> 32);
#pragma unroll
        for (int kk = 0; kk < 4; ++kk) {
            const int jo = c * 64 + kk * 16;
            float4 f0 = *(const float4*)(fdL + jo);
            float4 f1 = *(const float4*)(fdL + jo + 4);
            unsigned w32 = (kk < 2) ? bmlo : bmhi;
            unsigned m8 = (w32 >> ((kk & 1) * 16 + lq * 8)) & 0xffu;

            short8 af;
            const float* ff0 = (const float*)&f0;
            const float* ff1 = (const float*)&f1;
#pragma unroll
            for (int q = 0; q < 8; ++q) {
                float fdv = (q < 4) ? ff0[q] : ff1[q - 4];
                float y = fs + fdv;
                y = fmaxf(y, 0.2f * y);           // leaky_relu (log2-scaled domain)
                float e = exp2f(y);
                float p = (m8 & (1u << q)) ? e : 0.f;
                lp += p;
                af[q] = f2bf(p);
            }
            // B fragments direct from global (L1/L2-hot): B[k][n] = h_t[n][j0+k]
            short8 b0 = *(const short8*)(hb + 0 * 32 * NN + jo);
            short8 b1 = *(const short8*)(hb + 1 * 32 * NN + jo);
            short8 b2 = *(const short8*)(hb + 2 * 32 * NN + jo);
            short8 b3 = *(const short8*)(hb + 3 * 32 * NN + jo);
            acc[0] = __builtin_amdgcn_mfma_f32_32x32x16_bf16(af, b0, acc[0], 0, 0, 0);
            acc[1] = __builtin_amdgcn_mfma_f32_32x32x16_bf16(af, b1, acc[1], 0, 0, 0);
            acc[2] = __builtin_amdgcn_mfma_f32_32x32x16_bf16(af, b2, acc[2], 0, 0, 0);
            acc[3] = __builtin_amdgcn_mfma_f32_32x32x16_bf16(af, b3, acc[3], 0, 0, 0);
        }
    }

    // ---- partial row-sum l (feat-group 0 only; identical in group 1) ----
    lp += __shfl_xor(lp, 32);
    if (wc == 0 && lq == 0) lpart[(size_t)slice * NN + r] = lp;

    // ---- partial O:  C/D 32x32 mapping: col=l31, row=(reg&3)+8*(reg>>2)+4*lq ----
    float* ob = Opart + ((size_t)slice * NN + i0 + wr * 32) * FOUT + wc * 128;
#pragma unroll
    for (int nt = 0; nt < 4; nt++) {
        int n = nt * 32 + l31;
#pragma unroll
        for (int reg = 0; reg < 16; reg++) {
            int row = (reg & 3) + 8 * (reg >> 2) + 4 * lq;
            ob[(size_t)row * FOUT + n] = acc[nt][reg];
        }
    }
}

// ---------------- Kernel 3: combine partials: out = sum_s O_s / sum_s l_s ----------------
__global__ __launch_bounds__(256) void combine_kernel(const float* __restrict__ Opart,
                                                      const float* __restrict__ lpart,
                                                      float* __restrict__ out, int slices) {
    int i = blockIdx.x, n = threadIdx.x;
    float o = 0.f, l = 0.f;
    for (int s = 0; s < slices; s++) {
        o += Opart[((size_t)s * NN + i) * FOUT + n];
        l += lpart[(size_t)s * NN + i];
    }
    out[(size_t)i * FOUT + n] = o / l;
}

extern "C" void kernel_launch(void* const* d_in, const int* in_sizes, int n_in,
                              void* d_out, int out_size, void* d_ws, size_t ws_size,
                              hipStream_t stream) {
    const float* x   = (const float*)d_in[0];
    const int*   adj = (const int*)d_in[1];
    const float* W   = (const float*)d_in[2];
    const float* a   = (const float*)d_in[3];
    float* out = (float*)d_out;

    char* ws = (char*)d_ws;
    short* h_t   = (short*)ws;                                   // 0..4 MB
    short* Wt    = (short*)(ws + (4u << 20));                    // 256 KB
    float* f_src = (float*)(ws + (4u << 20) + (256u << 10));     // 32 KB
    float* f_dst = (float*)(ws + (4u << 20) + (288u << 10));     // 32 KB
    float* lpart = (float*)(ws + (4u << 20) + (320u << 10));     // 128 KB
    unsigned long long* pk64 = (unsigned long long*)(ws + (6u << 20));  // 8 MB
    float* Opart = (float*)(ws + (16u << 20));                   // 32 MB (4 slices)

    const int slices = 4;
    const int jlen = NN / slices;                                // 2048

    hipMemsetAsync(f_src, 0, 2 * NN * sizeof(float), stream);
    pack_kernel<<<2048, 256, 0, stream>>>(adj, pk64);
    wt_kernel<<<dim3(FIN / 32, FOUT / 32), 256, 0, stream>>>(W, Wt);
    h_kernel<<<1024, 256, 0, stream>>>(x, Wt, a, h_t, f_src, f_dst);
    gat_kernel<<<dim3(NN / 128, slices), 512, 0, stream>>>(pk64, h_t, f_src, f_dst,
                                                           Opart, lpart, jlen);
    combine_kernel<<<NN, 256, 0, stream>>>(Opart, lpart, out, slices);
}

// Round 5
// 524.291 us; speedup vs baseline: 1.0886x; 1.0886x over previous
//
#include <hip/hip_runtime.h>
#include <hip/hip_bf16.h>

#define NN 8192
#define FIN 512
#define FOUT 256

typedef __attribute__((ext_vector_type(8))) short short8;
typedef __attribute__((ext_vector_type(4))) float float4v;
typedef __attribute__((ext_vector_type(16))) float float16v;

__device__ __forceinline__ short f2bf(float f) {
    union { float f; unsigned u; } v; v.f = f;
    unsigned r = (v.u + 0x7FFFu + ((v.u >> 16) & 1u)) >> 16;
    return (short)r;
}

// ---------------- Kernel P: pack adj (256 MB) -> bitmask (8 MB), pure streaming ----------------
__global__ __launch_bounds__(256) void pack_kernel(const int* __restrict__ adj,
                                                   unsigned long long* __restrict__ pk64) {
    const int tid = blockIdx.x * 256 + threadIdx.x;
    const int stride = 2048 * 256;
#pragma unroll 8
    for (int k = 0; k < (NN * NN) / stride; ++k) {
        int idx = tid + k * stride;
        unsigned long long m = __ballot(adj[idx] != 0);
        if ((threadIdx.x & 63) == 0) pk64[idx >> 6] = m;
    }
}

// ---------------- Kernel 0: Wt[n][k] = bf16(W[k][n]), tiled transpose ----------------
__global__ __launch_bounds__(256) void wt_kernel(const float* __restrict__ W,
                                                 short* __restrict__ Wt) {
    __shared__ short tile[32][33];
    int tx = threadIdx.x & 31, ty = threadIdx.x >> 5;
    int k0 = blockIdx.x * 32, n0 = blockIdx.y * 32;
#pragma unroll
    for (int r = 0; r < 32; r += 8)
        tile[ty + r][tx] = f2bf(W[(size_t)(k0 + ty + r) * FOUT + n0 + tx]);
    __syncthreads();
#pragma unroll
    for (int r = 0; r < 32; r += 8)
        Wt[(size_t)(n0 + ty + r) * FIN + k0 + tx] = tile[tx][ty + r];
}

// ---------------- Kernel 1: h_t[n][m] = bf16((x@W)[m][n]); fused f_src/f_dst ----------------
// wave = 16m x 64n tile, 512 blocks x 4 waves (R3 config).
__global__ __launch_bounds__(256) void h_kernel(const float* __restrict__ x,
                                                const short* __restrict__ Wt,
                                                const float* __restrict__ a,
                                                short* __restrict__ h_t,
                                                float* __restrict__ f_src,
                                                float* __restrict__ f_dst) {
    int wave = (blockIdx.x << 2) + (threadIdx.x >> 6);
    int lane = threadIdx.x & 63;
    int m0 = (wave & 511) << 4;
    int n0 = (wave >> 9) << 6;
    int lr = lane & 15, lq = lane >> 4;

    const float* xrow = x + (size_t)(m0 + lr) * FIN + lq * 8;
    const short* wbase = Wt + (size_t)(n0 + lr) * FIN + lq * 8;

    float4v acc[4] = {};
    for (int k0 = 0; k0 < FIN; k0 += 32) {
        float4v xa = *(const float4v*)(xrow + k0);
        float4v xb = *(const float4v*)(xrow + k0 + 4);
        short8 av;
        av[0] = f2bf(xa[0]); av[1] = f2bf(xa[1]); av[2] = f2bf(xa[2]); av[3] = f2bf(xa[3]);
        av[4] = f2bf(xb[0]); av[5] = f2bf(xb[1]); av[6] = f2bf(xb[2]); av[7] = f2bf(xb[3]);
#pragma unroll
        for (int ct = 0; ct < 4; ct++) {
            short8 bv = *(const short8*)(wbase + (size_t)ct * 16 * FIN + k0);
            acc[ct] = __builtin_amdgcn_mfma_f32_16x16x32_bf16(av, bv, acc[ct], 0, 0, 0);
        }
    }
    float s_part[4] = {0.f, 0.f, 0.f, 0.f};
    float d_part[4] = {0.f, 0.f, 0.f, 0.f};
#pragma unroll
    for (int ct = 0; ct < 4; ct++) {
        int n = n0 + ct * 16 + lr;
        float al = a[n], ar = a[FOUT + n];
#pragma unroll
        for (int reg = 0; reg < 4; reg++) {
            float hv = acc[ct][reg];
            s_part[reg] = fmaf(hv, al, s_part[reg]);
            d_part[reg] = fmaf(hv, ar, d_part[reg]);
            h_t[(size_t)n * NN + (m0 + lq * 4 + reg)] = f2bf(hv);
        }
    }
#pragma unroll
    for (int off = 1; off < 16; off <<= 1) {
#pragma unroll
        for (int reg = 0; reg < 4; reg++) {
            s_part[reg] += __shfl_xor(s_part[reg], off);
            d_part[reg] += __shfl_xor(d_part[reg], off);
        }
    }
    const float LOG2E = 1.4426950408889634f;
    if (lr == 0) {
#pragma unroll
        for (int reg = 0; reg < 4; reg++) {
            atomicAdd(&f_src[m0 + lq * 4 + reg], s_part[reg] * LOG2E);
            atomicAdd(&f_dst[m0 + lq * 4 + reg], d_part[reg] * LOG2E);
        }
    }
}

// ---------------- Kernel 2: fused masked-softmax-numerator @ h ----------------
// Block 512 thr = 8 waves = 4 rowgroups x 2 featgroups; tile 128 rows x 256 feats.
// Wave: 32 rows x 128 feats = 4 acc tiles of 32x32x16 (64 acc VGPR).
// A (P) in registers from L2-resident bitmask + f_src/f_dst; B double-buffered in
// XOR-swizzled LDS, staged coalesced from L2-resident h_t. Grid 512 = 2 blocks/CU.
__global__ __launch_bounds__(512, 4) void gat_kernel(const unsigned long long* __restrict__ pk64,
                                                     const short* __restrict__ h_t,
                                                     const float* __restrict__ f_src,
                                                     const float* __restrict__ f_dst,
                                                     float* __restrict__ Opart,
                                                     float* __restrict__ lpart,
                                                     int jlen) {
    __shared__ short Ht[2][256 * 64];     // [buf][feat*64 + swizzled j], 64 KB

    const int t = threadIdx.x;
    const int lane = t & 63;
    const int w = t >> 6;
    const int l31 = lane & 31, lq = lane >> 5;
    const int wr = w & 3, wc = w >> 2;
    const int i0 = blockIdx.x * 128;
    const int slice = blockIdx.y;
    const int jbase = slice * jlen;
    const int r = i0 + wr * 32 + l31;
    const int nchunk = jlen >> 6;
    const int rsw = l31 & 7;              // read-side swizzle key

    const float fs = f_src[r];
    const unsigned long long* pkRow = pk64 + (size_t)r * (NN / 64) + (jbase >> 6);
    const float* fdL = f_dst + jbase + lq * 8;

    // staging role: thread t stages feat sf = t>>1, cols q = (t&1)*4 .. +3
    const int sf = t >> 1, sq0 = (t & 1) * 4;
    const short* hrow = h_t + (size_t)sf * NN + jbase + sq0 * 8;
    const int fsw = sf & 7;               // stage-side swizzle key
    short* HtW = &Ht[0][sf * 64];

    float16v acc[4] = {};
    float lp = 0.f;

    // ---- prologue: stage chunk 0 into buf 0; prefetch mask 0 ----
    {
        short8 s0 = *(const short8*)(hrow + 0);
        short8 s1 = *(const short8*)(hrow + 8);
        short8 s2 = *(const short8*)(hrow + 16);
        short8 s3 = *(const short8*)(hrow + 24);
        *(short8*)(HtW + (((sq0 + 0) ^ fsw) << 3)) = s0;
        *(short8*)(HtW + (((sq0 + 1) ^ fsw) << 3)) = s1;
        *(short8*)(HtW + (((sq0 + 2) ^ fsw) << 3)) = s2;
        *(short8*)(HtW + (((sq0 + 3) ^ fsw) << 3)) = s3;
    }
    unsigned long long bm = pkRow[0];
    __syncthreads();

    for (int c = 0; c < nchunk; ++c) {
        const int cn = (c + 1 < nchunk) ? c + 1 : 0;   // wrap: harmless re-stage
        // issue next chunk's staging loads + mask prefetch (L2-hot, covered by compute)
        short8 s0 = *(const short8*)(hrow + cn * 64 + 0);
        short8 s1 = *(const short8*)(hrow + cn * 64 + 8);
        short8 s2 = *(const short8*)(hrow + cn * 64 + 16);
        short8 s3 = *(const short8*)(hrow + cn * 64 + 24);
        unsigned long long bmn = pkRow[cn];

        const short* HtR = &Ht[c & 1][0];
        const unsigned bmlo = (unsigned)bm, bmhi = (unsigned)(bm >> 32);
#pragma unroll
        for (int kk = 0; kk < 4; ++kk) {
            const int jo = c * 64 + kk * 16;
            float4 f0 = *(const float4*)(fdL + jo);
            float4 f1 = *(const float4*)(fdL + jo + 4);
            unsigned w32 = (kk < 2) ? bmlo : bmhi;
            unsigned m8 = (w32 >> ((kk & 1) * 16 + lq * 8)) & 0xffu;

            short8 af;
            const float* ff0 = (const float*)&f0;
            const float* ff1 = (const float*)&f1;
#pragma unroll
            for (int q = 0; q < 8; ++q) {
                float fdv = (q < 4) ? ff0[q] : ff1[q - 4];
                float y = fs + fdv;
                y = fmaxf(y, 0.2f * y);            // leaky_relu (log2-scaled domain)
                float e = exp2f(y);
                float p = (m8 & (1u << q)) ? e : 0.f;
                lp += p;
                af[q] = f2bf(p);
            }
            const int cb = ((kk * 2 + lq) ^ rsw) << 3;
#pragma unroll
            for (int nt = 0; nt < 4; nt++) {
                const int feat = wc * 128 + nt * 32 + l31;
                short8 b = *(const short8*)(HtR + feat * 64 + cb);
                acc[nt] = __builtin_amdgcn_mfma_f32_32x32x16_bf16(af, b, acc[nt], 0, 0, 0);
            }
        }
        // write next chunk into the other buffer
        short* HtN = &Ht[(c & 1) ^ 1][sf * 64];
        *(short8*)(HtN + (((sq0 + 0) ^ fsw) << 3)) = s0;
        *(short8*)(HtN + (((sq0 + 1) ^ fsw) << 3)) = s1;
        *(short8*)(HtN + (((sq0 + 2) ^ fsw) << 3)) = s2;
        *(short8*)(HtN + (((sq0 + 3) ^ fsw) << 3)) = s3;
        bm = bmn;
        __syncthreads();
    }

    // ---- partial row-sum l (featgroup 0 only; featgroup 1 identical) ----
    lp += __shfl_xor(lp, 32);
    if (wc == 0 && lq == 0) lpart[(size_t)slice * NN + r] = lp;

    // ---- partial O: C/D 32x32 mapping: col=l31, row=(reg&3)+8*(reg>>2)+4*lq ----
    float* ob = Opart + ((size_t)slice * NN + i0 + wr * 32) * FOUT + wc * 128;
#pragma unroll
    for (int nt = 0; nt < 4; nt++) {
        int n = nt * 32 + l31;
#pragma unroll
        for (int reg = 0; reg < 16; reg++) {
            int row = (reg & 3) + 8 * (reg >> 2) + 4 * lq;
            ob[(size_t)row * FOUT + n] = acc[nt][reg];
        }
    }
}

// ---------------- Kernel 3: combine partials: out = sum_s O_s / sum_s l_s ----------------
__global__ __launch_bounds__(256) void combine_kernel(const float* __restrict__ Opart,
                                                      const float* __restrict__ lpart,
                                                      float* __restrict__ out, int slices) {
    int i = blockIdx.x, n = threadIdx.x;
    float o = 0.f, l = 0.f;
    for (int s = 0; s < slices; s++) {
        o += Opart[((size_t)s * NN + i) * FOUT + n];
        l += lpart[(size_t)s * NN + i];
    }
    out[(size_t)i * FOUT + n] = o / l;
}

extern "C" void kernel_launch(void* const* d_in, const int* in_sizes, int n_in,
                              void* d_out, int out_size, void* d_ws, size_t ws_size,
                              hipStream_t stream) {
    const float* x   = (const float*)d_in[0];
    const int*   adj = (const int*)d_in[1];
    const float* W   = (const float*)d_in[2];
    const float* a   = (const float*)d_in[3];
    float* out = (float*)d_out;

    char* ws = (char*)d_ws;
    short* h_t   = (short*)ws;                                   // 0..4 MB
    short* Wt    = (short*)(ws + (4u << 20));                    // 256 KB
    float* f_src = (float*)(ws + (4u << 20) + (256u << 10));     // 32 KB
    float* f_dst = (float*)(ws + (4u << 20) + (288u << 10));     // 32 KB
    float* lpart = (float*)(ws + (4u << 20) + (320u << 10));     // 256 KB
    unsigned long long* pk64 = (unsigned long long*)(ws + (6u << 20));  // 8 MB
    float* Opart = (float*)(ws + (16u << 20));                   // 64 MB (8 slices)

    const int slices = 8;
    const int jlen = NN / slices;                                // 1024

    hipMemsetAsync(f_src, 0, 2 * NN * sizeof(float), stream);
    pack_kernel<<<2048, 256, 0, stream>>>(adj, pk64);
    wt_kernel<<<dim3(FIN / 32, FOUT / 32), 256, 0, stream>>>(W, Wt);
    h_kernel<<<512, 256, 0, stream>>>(x, Wt, a, h_t, f_src, f_dst);
    gat_kernel<<<dim3(NN / 128, slices), 512, 0, stream>>>(pk64, h_t, f_src, f_dst,
                                                           Opart, lpart, jlen);
    combine_kernel<<<NN, 256, 0, stream>>>(Opart, lpart, out, slices);
}